// Round 10
// baseline (169.174 us; speedup 1.0000x reference)
//
#include <hip/hip_runtime.h>
#include <stdint.h>

#define MD 4096
#define ND 4096
#define KD 4096
#define BK 32
#define NT (KD / BK)   // 128 K-tiles
#define REGA 8192      // A buf region elems (256x32)
#define REGB 4096      // B buf region elems (128x32)
#define BBASE 24576    // 3*REGA

typedef __bf16 bf16x8 __attribute__((ext_vector_type(8)));
typedef float f32x4 __attribute__((ext_vector_type(4)));

__device__ __forceinline__ uint32_t f32_to_bf16(float f) {
    union { float f; uint32_t u; } v; v.f = f;
    return (v.u + 0x7FFFu + ((v.u >> 16) & 1u)) >> 16;
}

#define GLDS16(gp, lp) \
    __builtin_amdgcn_global_load_lds((const __attribute__((address_space(1))) void*)(gp), \
                                     (__attribute__((address_space(3))) void*)(lp), 16, 0, 0)

// ---------------------------------------------------------------------------
// Dequant (separate kernels: merged prep measured ~9-11 us slower, R2 vs R3-R9)
// ---------------------------------------------------------------------------
__global__ void dq_kernel(const int* __restrict__ Wq,
                          const float* __restrict__ scale,
                          const float* __restrict__ zero,
                          uint16_t* __restrict__ Wb) {
    int t = blockIdx.x * 256 + threadIdx.x;
    int o  = t >> 9;
    int i0 = (t & 511) << 3;
    const uint4* wp = (const uint4*)Wq;
    uint4 pa = wp[t * 2], pb = wp[t * 2 + 1];
    uint32_t v[8] = {pa.x, pa.y, pa.z, pa.w, pb.x, pb.y, pb.z, pb.w};
    int gh = (o << 6) + (i0 >> 6);
    int gl = gh + (2048 << 6);
    float sh = scale[gh], zh = zero[gh];
    float sl = scale[gl], zl = zero[gl];
    uint32_t hw[4], lw[4];
#pragma unroll
    for (int p = 0; p < 4; ++p) {
        uint32_t b0 = v[p * 2], b1 = v[p * 2 + 1];
        uint32_t h0 = f32_to_bf16(((float)((b0 >> 4) & 15u) - zh) * sh);
        uint32_t h1 = f32_to_bf16(((float)((b1 >> 4) & 15u) - zh) * sh);
        uint32_t l0 = f32_to_bf16(((float)(b0 & 15u) - zl) * sl);
        uint32_t l1 = f32_to_bf16(((float)(b1 & 15u) - zl) * sl);
        hw[p] = h0 | (h1 << 16);
        lw[p] = l0 | (l1 << 16);
    }
    uint4 hv = {hw[0], hw[1], hw[2], hw[3]};
    uint4 lv = {lw[0], lw[1], lw[2], lw[3]};
    *(uint4*)&Wb[(size_t)o * KD + i0]          = hv;
    *(uint4*)&Wb[(size_t)(o + 2048) * KD + i0] = lv;
}

__global__ void xc_kernel(const float* __restrict__ x, uint16_t* __restrict__ xb) {
    int t = blockIdx.x * 256 + threadIdx.x;
    const float4* xp = (const float4*)x;
    float4 a = xp[t * 2], b = xp[t * 2 + 1];
    uint4 o;
    o.x = f32_to_bf16(a.x) | (f32_to_bf16(a.y) << 16);
    o.y = f32_to_bf16(a.z) | (f32_to_bf16(a.w) << 16);
    o.z = f32_to_bf16(b.x) | (f32_to_bf16(b.y) << 16);
    o.w = f32_to_bf16(b.z) | (f32_to_bf16(b.w) << 16);
    ((uint4*)xb)[t] = o;
}

// ---------------------------------------------------------------------------
// GEMM: 256x128 tile, BK=32, 8 waves (4Mx2N of 64x64), 512 threads,
// 3-deep LDS pipeline (72 KiB -> 2 blocks/CU, 16 waves/CU): cross-BLOCK
// overlap hides barrier/VM stalls (m114 mechanism) instead of intra-block
// scheduling. Per tile: stage(t+2)->buf pc [3 gload_lds/thread]; ds_read
// buf pa (8x b128); lgkm0; 16 MFMA; VM(3) drains t+1's stages (issued one
// full tile ~2000cyc ago >> 900cyc HBM); BAR; rotate bufs.
// Swizzle identical to R9 (verified conflict-free): read sx=ls^((lr>>1)&3),
// source pre-swizzle sslot=(tid&3)^((tid>>3)&3)  (rule #21).
// ---------------------------------------------------------------------------
#define BAR()  asm volatile("s_barrier" ::: "memory")
#define LGKM0() do { asm volatile("s_waitcnt lgkmcnt(0)" ::: "memory"); \
                     __builtin_amdgcn_sched_barrier(0); } while (0)
#define VM(N)  asm volatile("s_waitcnt vmcnt(" #N ")" ::: "memory")

#define STAGE_A(P, KB) do {                                                           \
    GLDS16(Ag + (size_t)(tid >> 2) * KD + (KB) + sslot * 8,                           \
           lds + (P) * REGA + tid * 8);                                               \
    GLDS16(Ag + (size_t)(128 + (tid >> 2)) * KD + (KB) + sslot * 8,                   \
           lds + (P) * REGA + 4096 + tid * 8);                                        \
} while (0)

#define STAGE_B(P, KB)                                                                \
    GLDS16(Bg + (size_t)(tid >> 2) * KD + (KB) + sslot * 8,                           \
           lds + BBASE + (P) * REGB + tid * 8)

#define RD_A(P) do {                                                                  \
    const uint16_t* _Ar = lds + (P) * REGA;                                           \
    _Pragma("unroll")                                                                 \
    for (int m = 0; m < 4; ++m)                                                       \
        a[m] = *(const bf16x8*)&_Ar[(wr * 64 + m * 16 + lr) * 32 + sx * 8];           \
} while (0)

#define RD_B(P) do {                                                                  \
    const uint16_t* _Br = lds + BBASE + (P) * REGB;                                   \
    _Pragma("unroll")                                                                 \
    for (int n = 0; n < 4; ++n)                                                       \
        b[n] = *(const bf16x8*)&_Br[(wc * 64 + n * 16 + lr) * 32 + sx * 8];           \
} while (0)

#define MFQ() do {                                                                    \
    __builtin_amdgcn_s_setprio(1);                                                    \
    _Pragma("unroll")                                                                 \
    for (int m = 0; m < 4; ++m)                                                       \
    _Pragma("unroll")                                                                 \
    for (int n = 0; n < 4; ++n)                                                       \
        acc[m][n] = __builtin_amdgcn_mfma_f32_16x16x32_bf16(                          \
            a[m], b[n], acc[m][n], 0, 0, 0);                                          \
    __builtin_amdgcn_s_setprio(0);                                                    \
} while (0)

__global__ __launch_bounds__(512, 4)
void gemm_kernel(const uint16_t* __restrict__ A,
                 const uint16_t* __restrict__ B,
                 float* __restrict__ C) {
    __shared__ uint16_t lds[36864];   // 72 KiB: 3x(256x32 A) + 3x(128x32 B)

    const int tid  = threadIdx.x;
    const int wave = tid >> 6;
    const int lane = tid & 63;
    const int wr = wave >> 1;                  // 0..3
    const int wc = wave & 1;                   // 0..1
    const int lr = lane & 15;
    const int ls = lane >> 4;
    const int sx = ls ^ ((lr >> 1) & 3);              // swizzled read slot
    const int sslot = (tid & 3) ^ ((tid >> 3) & 3);   // pre-swizzled stage slot

    // XCD-aware swizzle: 512 wgs, 8 XCDs, 64 contiguous tiles per XCD
    int bid = blockIdx.x;
    int wg = (bid & 7) * 64 + (bid >> 3);
    const int bm0 = (wg >> 5) * 256;           // 16 M-tiles
    const int bn0 = (wg & 31) * 128;           // 32 N-tiles

    const uint16_t* Ag = A + (size_t)bm0 * KD;
    const uint16_t* Bg = B + (size_t)bn0 * KD;

    f32x4 acc[4][4];
#pragma unroll
    for (int m = 0; m < 4; ++m)
#pragma unroll
        for (int n = 0; n < 4; ++n) {
            f32x4 z = {0.f, 0.f, 0.f, 0.f};
            acc[m][n] = z;
        }

    bf16x8 a[4], b[4];

    // prologue: tile0 -> buf0, tile1 -> buf1; drain tile0 (VM(3) leaves t1's 3)
    STAGE_A(0, 0);      STAGE_B(0, 0);
    STAGE_A(1, BK);     STAGE_B(1, BK);
    VM(3);
    BAR();

    int pa = 0, pb = 1, pc = 2;
#pragma unroll 1
    for (int t = 0; t < NT - 1; ++t) {
        const int kn = (t + 2) * BK;
        if (t < NT - 2) { STAGE_A(pc, kn); STAGE_B(pc, kn); }
        RD_A(pa); RD_B(pa);
        LGKM0();
        MFQ();
        if (t < NT - 2) { VM(3); } else { VM(0); }
        BAR();
        int tmp = pa; pa = pb; pb = pc; pc = tmp;
    }
    // tail tile NT-1
    {
        RD_A(pa); RD_B(pa);
        LGKM0();
        MFQ();
    }

    // epilogue: D layout col=lane&15, row=(lane>>4)*4+r  [m89/m91]
    const int r0 = ls * 4;
#pragma unroll
    for (int m = 0; m < 4; ++m)
#pragma unroll
        for (int n = 0; n < 4; ++n)
#pragma unroll
            for (int r = 0; r < 4; ++r) {
                int row = bm0 + wr * 64 + m * 16 + r0 + r;
                int col = bn0 + wc * 64 + n * 16 + lr;
                C[(size_t)row * ND + col] = acc[m][n][r];
            }
}

extern "C" void kernel_launch(void* const* d_in, const int* in_sizes, int n_in,
                              void* d_out, int out_size, void* d_ws, size_t ws_size,
                              hipStream_t stream) {
    const float* x     = (const float*)d_in[0];
    const int*   Wq    = (const int*)d_in[1];
    const float* scale = (const float*)d_in[2];
    const float* zero  = (const float*)d_in[3];
    float* out = (float*)d_out;

    uint16_t* Wb = (uint16_t*)d_ws;                                     // 32 MB
    uint16_t* xb = (uint16_t*)((char*)d_ws + (size_t)32 * 1024 * 1024); // 32 MB

    hipLaunchKernelGGL(dq_kernel, dim3(4096), dim3(256), 0, stream, Wq, scale, zero, Wb);
    hipLaunchKernelGGL(xc_kernel, dim3(8192), dim3(256), 0, stream, x, xb);
    hipLaunchKernelGGL(gemm_kernel, dim3(512), dim3(512), 0, stream, xb, Wb, out);
}

// Round 11
// 148.160 us; speedup vs baseline: 1.1418x; 1.1418x over previous
//
#include <hip/hip_runtime.h>
#include <stdint.h>

#define MD 4096
#define ND 4096
#define KD 4096
#define BK 64
#define NT (KD / BK)   // 64 K-tiles

typedef __bf16 bf16x8 __attribute__((ext_vector_type(8)));
typedef float f32x4 __attribute__((ext_vector_type(4)));

__device__ __forceinline__ uint32_t f32_to_bf16(float f) {
    union { float f; uint32_t u; } v; v.f = f;
    return (v.u + 0x7FFFu + ((v.u >> 16) & 1u)) >> 16;
}

#define GLDS16(gp, lp) \
    __builtin_amdgcn_global_load_lds((const __attribute__((address_space(1))) void*)(gp), \
                                     (__attribute__((address_space(3))) void*)(lp), 16, 0, 0)

// ---------------------------------------------------------------------------
// Dequant + convert (separate kernels — merged prep measured slower R3-R9)
// ---------------------------------------------------------------------------
__global__ void dq_kernel(const int* __restrict__ Wq,
                          const float* __restrict__ scale,
                          const float* __restrict__ zero,
                          uint16_t* __restrict__ Wb) {
    int t = blockIdx.x * 256 + threadIdx.x;
    int o  = t >> 9;
    int i0 = (t & 511) << 3;
    const uint4* wp = (const uint4*)Wq;
    uint4 pa = wp[t * 2], pb = wp[t * 2 + 1];
    uint32_t v[8] = {pa.x, pa.y, pa.z, pa.w, pb.x, pb.y, pb.z, pb.w};
    int gh = (o << 6) + (i0 >> 6);
    int gl = gh + (2048 << 6);
    float sh = scale[gh], zh = zero[gh];
    float sl = scale[gl], zl = zero[gl];
    uint32_t hw[4], lw[4];
#pragma unroll
    for (int p = 0; p < 4; ++p) {
        uint32_t b0 = v[p * 2], b1 = v[p * 2 + 1];
        uint32_t h0 = f32_to_bf16(((float)((b0 >> 4) & 15u) - zh) * sh);
        uint32_t h1 = f32_to_bf16(((float)((b1 >> 4) & 15u) - zh) * sh);
        uint32_t l0 = f32_to_bf16(((float)(b0 & 15u) - zl) * sl);
        uint32_t l1 = f32_to_bf16(((float)(b1 & 15u) - zl) * sl);
        hw[p] = h0 | (h1 << 16);
        lw[p] = l0 | (l1 << 16);
    }
    uint4 hv = {hw[0], hw[1], hw[2], hw[3]};
    uint4 lv = {lw[0], lw[1], lw[2], lw[3]};
    *(uint4*)&Wb[(size_t)o * KD + i0]          = hv;
    *(uint4*)&Wb[(size_t)(o + 2048) * KD + i0] = lv;
}

__global__ void xc_kernel(const float* __restrict__ x, uint16_t* __restrict__ xb) {
    int t = blockIdx.x * 256 + threadIdx.x;
    const float4* xp = (const float4*)x;
    float4 a = xp[t * 2], b = xp[t * 2 + 1];
    uint4 o;
    o.x = f32_to_bf16(a.x) | (f32_to_bf16(a.y) << 16);
    o.y = f32_to_bf16(a.z) | (f32_to_bf16(a.w) << 16);
    o.z = f32_to_bf16(b.x) | (f32_to_bf16(b.y) << 16);
    o.w = f32_to_bf16(b.z) | (f32_to_bf16(b.w) << 16);
    ((uint4*)xb)[t] = o;
}

// ---------------------------------------------------------------------------
// GEMM: 256x256 tile, BK=64, 16 waves (4Mx4N of 64x64) @ 1024 threads.
// ONE barrier per K-tile (R9 had two): stages for t+1 issued first (max age
// at the drain), then all kh0 reads + kh1 A reads (12x b128), counted
// lgkmcnt(4) -> MFQ0 overlaps kh1 completions; b1 reads; lgkmcnt(0) -> MFQ1;
// vmcnt(0) (stages ~2 MFQ clusters old, L2-hit latency -> near-free) + BAR.
// Races: stages target opposite buffer, read-protected by previous tile-end
// barrier; VM(0)+BAR collectivizes stage visibility before t+1 reads.
// Register budget: frags a0,b0,a1,b1 = 64 VGPR + acc 64 (unified) + addr
// ~= 125 <= 128 keeps 4 waves/SIMD (m69 cliff at 128).
// LDS region(buf,mat,kh) = [256 rows][32 k] bf16 (16 KiB); 8 regions=128 KiB.
// Swizzle (verified 0-conflict): read sx=ls^((lr>>1)&3); stage source
// pre-swizzle sslot=(tid&3)^((tid>>3)&3), linear LDS dest (rule #21).
// ---------------------------------------------------------------------------
#define BAR()  asm volatile("s_barrier" ::: "memory")
#define LGKM(N) do { asm volatile("s_waitcnt lgkmcnt(" #N ")" ::: "memory"); \
                     __builtin_amdgcn_sched_barrier(0); } while (0)
#define VM(N)  asm volatile("s_waitcnt vmcnt(" #N ")" ::: "memory")

#define STAGE(PTR, BUF, MAT, KH, KBASE) \
    GLDS16((PTR) + (size_t)grow * KD + (KBASE) + (KH) * 32 + sslot * 8, \
           lds + (((BUF) * 2 + (MAT)) * 2 + (KH)) * 8192 + tid * 8)

#define RD_A(DST, P, KH) do {                                                         \
    const uint16_t* _Ar = lds + (((P) * 2 + 0) * 2 + (KH)) * 8192;                    \
    _Pragma("unroll")                                                                 \
    for (int m = 0; m < 4; ++m)                                                       \
        DST[m] = *(const bf16x8*)&_Ar[(wr * 64 + m * 16 + lr) * 32 + sx * 8];         \
} while (0)

#define RD_B(DST, P, KH) do {                                                         \
    const uint16_t* _Br = lds + (((P) * 2 + 1) * 2 + (KH)) * 8192;                    \
    _Pragma("unroll")                                                                 \
    for (int n = 0; n < 4; ++n)                                                       \
        DST[n] = *(const bf16x8*)&_Br[(wc * 64 + n * 16 + lr) * 32 + sx * 8];         \
} while (0)

#define MFQ(AS, BS) do {                                                              \
    __builtin_amdgcn_s_setprio(1);                                                    \
    _Pragma("unroll")                                                                 \
    for (int m = 0; m < 4; ++m)                                                       \
    _Pragma("unroll")                                                                 \
    for (int n = 0; n < 4; ++n)                                                       \
        acc[m][n] = __builtin_amdgcn_mfma_f32_16x16x32_bf16(                          \
            AS[m], BS[n], acc[m][n], 0, 0, 0);                                        \
    __builtin_amdgcn_s_setprio(0);                                                    \
} while (0)

__global__ __launch_bounds__(1024, 4)
void gemm_kernel(const uint16_t* __restrict__ A,
                 const uint16_t* __restrict__ B,
                 float* __restrict__ C) {
    __shared__ uint16_t lds[65536];   // 128 KiB

    const int tid  = threadIdx.x;
    const int wave = tid >> 6;
    const int lane = tid & 63;
    const int wr = wave >> 2;                  // 0..3
    const int wc = wave & 3;                   // 0..3
    const int lr = lane & 15;
    const int ls = lane >> 4;
    const int sx = ls ^ ((lr >> 1) & 3);              // swizzled read slot
    const int sslot = (tid & 3) ^ ((tid >> 3) & 3);   // pre-swizzled stage slot
    const int grow  = tid >> 2;                       // 0..255 staging row

    // XCD-aware swizzle: 256 wgs, 8 XCDs, 32 contiguous tiles per XCD
    int bid = blockIdx.x;
    int wg = (bid & 7) * 32 + (bid >> 3);
    const int bm0 = (wg >> 4) * 256;
    const int bn0 = (wg & 15) * 256;

    const uint16_t* Ag = A + (size_t)bm0 * KD;
    const uint16_t* Bg = B + (size_t)bn0 * KD;

    f32x4 acc[4][4];
#pragma unroll
    for (int m = 0; m < 4; ++m)
#pragma unroll
        for (int n = 0; n < 4; ++n) {
            f32x4 z = {0.f, 0.f, 0.f, 0.f};
            acc[m][n] = z;
        }

    bf16x8 a0[4], b0[4], a1[4], b1[4];

    // prologue: stage tile 0 fully into buf0, drain, barrier
    STAGE(Ag, 0, 0, 0, 0);
    STAGE(Bg, 0, 1, 0, 0);
    STAGE(Ag, 0, 0, 1, 0);
    STAGE(Bg, 0, 1, 1, 0);
    VM(0);
    BAR();

#pragma unroll 1
    for (int t = 0; t < NT - 1; ++t) {          // tiles 0..62 (tail = 63)
        const int p = t & 1, q = p ^ 1;
        const int kn = (t + 1) * BK;
        // stages first (maximize age at the tile-end drain)
        STAGE(Ag, q, 0, 0, kn);
        STAGE(Bg, q, 1, 0, kn);
        STAGE(Ag, q, 0, 1, kn);
        STAGE(Bg, q, 1, 1, kn);
        // front-loaded reads: kh0 A,B then kh1 A  (12 x b128)
        RD_A(a0, p, 0); RD_B(b0, p, 0);
        RD_A(a1, p, 1);
        LGKM(4);                                // a0,b0 home; a1 in flight
        MFQ(a0, b0);                            // covers a1/b1 latency
        RD_B(b1, p, 1);
        LGKM(0);                                // a1,b1 home
        MFQ(a1, b1);
        VM(0);                                  // stages ~2 MFQ clusters old
        BAR();
    }
    // tail tile t = NT-1 (p=1): no staging
    {
        RD_A(a0, 1, 0); RD_B(b0, 1, 0);
        RD_A(a1, 1, 1);
        LGKM(4);
        MFQ(a0, b0);
        RD_B(b1, 1, 1);
        LGKM(0);
        MFQ(a1, b1);
    }

    // epilogue: D layout col=lane&15, row=(lane>>4)*4+r  [m89/m91]
    const int r0 = ls * 4;
#pragma unroll
    for (int m = 0; m < 4; ++m)
#pragma unroll
        for (int n = 0; n < 4; ++n)
#pragma unroll
            for (int r = 0; r < 4; ++r) {
                int row = bm0 + wr * 64 + m * 16 + r0 + r;
                int col = bn0 + wc * 64 + n * 16 + lr;
                C[(size_t)row * ND + col] = acc[m][n][r];
            }
}

extern "C" void kernel_launch(void* const* d_in, const int* in_sizes, int n_in,
                              void* d_out, int out_size, void* d_ws, size_t ws_size,
                              hipStream_t stream) {
    const float* x     = (const float*)d_in[0];
    const int*   Wq    = (const int*)d_in[1];
    const float* scale = (const float*)d_in[2];
    const float* zero  = (const float*)d_in[3];
    float* out = (float*)d_out;

    uint16_t* Wb = (uint16_t*)d_ws;                                     // 32 MB
    uint16_t* xb = (uint16_t*)((char*)d_ws + (size_t)32 * 1024 * 1024); // 32 MB

    hipLaunchKernelGGL(dq_kernel, dim3(4096), dim3(256), 0, stream, Wq, scale, zero, Wb);
    hipLaunchKernelGGL(xc_kernel, dim3(8192), dim3(256), 0, stream, x, xb);
    hipLaunchKernelGGL(gemm_kernel, dim3(256), dim3(1024), 0, stream, xb, Wb, out);
}